// Round 1
// baseline (745.442 us; speedup 1.0000x reference)
//
#include <hip/hip_runtime.h>
#include <hip/hip_bf16.h>

// FuncSelfAttention: b=4, s=256, E=256, H=8, d=32, spatial 16x16 (p=256)
// All internal GEMMs in bf16 MFMA (16x16x32), fp32 accumulate.
//
// Pipeline:
//   k_qkv     : per bs: [768x256] x [256x256] -> Q,K,V bf16 ([b,h,s,d,p] layout)
//   k_scores  : per bh: Q[256x8192] K^T       -> scores f32 [bh,q,k]
//   k_softmax : row softmax                   -> P bf16 [bh,q,k]
//   k_av      : per bh: P[256x256] V[256x8192]-> SA bf16 [bs,c,p]
//   k_out     : per bs: W_out SA + b          -> out f32
//
// Q,K are stored in d_out (exactly 256 MiB) and overwritten by k_out at the end.
// d_ws holds V (128 MiB) + SA (128 MiB) + scores (8 MiB) + P (4 MiB).

#define DI __device__ __forceinline__

typedef __attribute__((ext_vector_type(4))) float  f32x4;
typedef __attribute__((ext_vector_type(8))) short  s16x8;
typedef __attribute__((ext_vector_type(4))) short  s16x4;
typedef __attribute__((ext_vector_type(8))) __bf16 bf16x8;

DI unsigned short f2bf(float f) {
    unsigned int u = __builtin_bit_cast(unsigned int, f);
    u = (u + 0x7fffu + ((u >> 16) & 1u)) >> 16;
    return (unsigned short)u;
}
DI bf16x8 asbf(s16x8 v) { return __builtin_bit_cast(bf16x8, v); }

#define MFMA16(a, b, c) __builtin_amdgcn_mfma_f32_16x16x32_bf16((a), (b), (c), 0, 0, 0)

// ---------------------------------------------------------------------------
// Kernel 1: QKV projection.  grid (6, 1024), block 256.
// Per block: rows [mt*128, mt*128+128) of W_qkv x seq_bs[256c x 256p].
// Wave layout: 4 waves, each [128 m x 64 n]; m-frags 8, n-frags 4.
// ---------------------------------------------------------------------------
__global__ __launch_bounds__(256, 2) void k_qkv(
    const float* __restrict__ seq, const float* __restrict__ W,
    unsigned short* __restrict__ Qb, unsigned short* __restrict__ Kb,
    unsigned short* __restrict__ Vb)
{
    const int bs = blockIdx.y;
    const int mt = blockIdx.x;
    const int b = bs >> 8, s = bs & 255;
    const int tid = threadIdx.x;
    const int wv = tid >> 6, ln = tid & 63;
    const int lg = ln >> 4, lr = ln & 15;
    const int n0 = wv * 64;

    __shared__ __align__(16) unsigned short Al[128][72];   // W chunk [128 m][32 k], pad
    __shared__ __align__(16) unsigned short Bl[32][264];   // seq chunk [32 k][256 n], pad

    f32x4 acc[8][4];
    const f32x4 z4 = {0.f, 0.f, 0.f, 0.f};
#pragma unroll
    for (int m = 0; m < 8; m++)
#pragma unroll
        for (int n = 0; n < 4; n++) acc[m][n] = z4;

    const float* Wt = W + (size_t)mt * 128 * 256;
    const float* Sq = seq + (size_t)bs * 65536;

    for (int k0 = 0; k0 < 256; k0 += 32) {
        {   // stage A (W rows, fp32 -> bf16): 128x32, 16 el/thread
            int r = tid >> 1, c0 = (tid & 1) * 16;
            const float* src = Wt + (size_t)r * 256 + k0 + c0;
#pragma unroll
            for (int i = 0; i < 4; i++) {
                f32x4 v = *(const f32x4*)(src + i * 4);
                s16x4 h = {(short)f2bf(v.x), (short)f2bf(v.y), (short)f2bf(v.z), (short)f2bf(v.w)};
                *(s16x4*)&Al[r][c0 + i * 4] = h;
            }
        }
        {   // stage B (seq rows, fp32 -> bf16): 32x256, 32 el/thread
            int r = tid >> 3, c0 = (tid & 7) * 32;
            const float* src = Sq + (size_t)(k0 + r) * 256 + c0;
#pragma unroll
            for (int i = 0; i < 8; i++) {
                f32x4 v = *(const f32x4*)(src + i * 4);
                s16x4 h = {(short)f2bf(v.x), (short)f2bf(v.y), (short)f2bf(v.z), (short)f2bf(v.w)};
                *(s16x4*)&Bl[r][c0 + i * 4] = h;
            }
        }
        __syncthreads();

        s16x8 af[8];
#pragma unroll
        for (int m = 0; m < 8; m++)
            af[m] = *(const s16x8*)&Al[m * 16 + lr][lg * 8];
#pragma unroll
        for (int n = 0; n < 4; n++) {
            s16x8 bf;
            int col = n0 + n * 16 + lr;
#pragma unroll
            for (int j = 0; j < 8; j++) bf[j] = (short)Bl[lg * 8 + j][col];
            bf16x8 bv = asbf(bf);
#pragma unroll
            for (int m = 0; m < 8; m++)
                acc[m][n] = MFMA16(asbf(af[m]), bv, acc[m][n]);
        }
        __syncthreads();
    }

    // epilogue: scatter rows into Q/K/V per channel-layout o = head*96 + split*32 + dd
#pragma unroll
    for (int m = 0; m < 8; m++) {
#pragma unroll
        for (int r = 0; r < 4; r++) {
            int o = mt * 128 + m * 16 + lg * 4 + r;
            int head = o / 96;
            int rem = o - head * 96;
            int sp = rem >> 5;
            int dd = rem & 31;
            unsigned short* dst = (sp == 0) ? Qb : (sp == 1) ? Kb : Vb;
            size_t base = ((size_t)((b * 8 + head) * 256 + s)) * 8192 + (size_t)dd * 256;
#pragma unroll
            for (int n = 0; n < 4; n++)
                dst[base + n0 + n * 16 + lr] = f2bf(acc[m][n][r]);
        }
    }
}

// ---------------------------------------------------------------------------
// Kernel 2a: scores = Q K^T * scale.  grid (8, 32), block 256.
// Per block: [64 q x 128 ks] over K=8192.  Wave: [64 m x 32 n].
// ---------------------------------------------------------------------------
__global__ __launch_bounds__(256, 2) void k_scores(
    const unsigned short* __restrict__ Qb, const unsigned short* __restrict__ Kb,
    float* __restrict__ Sc)
{
    const int bh = blockIdx.y;
    const int qt = blockIdx.x >> 1;
    const int kt = blockIdx.x & 1;
    const int q0 = qt * 64, ks0 = kt * 128;
    const int tid = threadIdx.x;
    const int wv = tid >> 6, ln = tid & 63;
    const int lg = ln >> 4, lr = ln & 15;
    const int n0 = wv * 32;

    __shared__ __align__(16) unsigned short Ql[64][72];
    __shared__ __align__(16) unsigned short Kl[128][72];

    f32x4 acc[4][2];
    const f32x4 z4 = {0.f, 0.f, 0.f, 0.f};
#pragma unroll
    for (int m = 0; m < 4; m++)
#pragma unroll
        for (int n = 0; n < 2; n++) acc[m][n] = z4;

    const unsigned short* Qsrc = Qb + (size_t)(bh * 256 + q0) * 8192;
    const unsigned short* Ksrc = Kb + (size_t)(bh * 256 + ks0) * 8192;

    for (int f0 = 0; f0 < 8192; f0 += 64) {
        {   // stage Q 64x64
            int r = tid >> 2, c0 = (tid & 3) * 16;
            const unsigned short* src = Qsrc + (size_t)r * 8192 + f0 + c0;
            *(s16x8*)&Ql[r][c0] = *(const s16x8*)(src);
            *(s16x8*)&Ql[r][c0 + 8] = *(const s16x8*)(src + 8);
        }
        {   // stage K 128x64
            int r = tid >> 1, c0 = (tid & 1) * 32;
            const unsigned short* src = Ksrc + (size_t)r * 8192 + f0 + c0;
#pragma unroll
            for (int i = 0; i < 4; i++)
                *(s16x8*)&Kl[r][c0 + i * 8] = *(const s16x8*)(src + i * 8);
        }
        __syncthreads();
#pragma unroll
        for (int kk = 0; kk < 2; kk++) {
            s16x8 af[4];
#pragma unroll
            for (int m = 0; m < 4; m++)
                af[m] = *(const s16x8*)&Ql[m * 16 + lr][kk * 32 + lg * 8];
#pragma unroll
            for (int n = 0; n < 2; n++) {
                s16x8 bf = *(const s16x8*)&Kl[n0 + n * 16 + lr][kk * 32 + lg * 8];
                bf16x8 bv = asbf(bf);
#pragma unroll
                for (int m = 0; m < 4; m++)
                    acc[m][n] = MFMA16(asbf(af[m]), bv, acc[m][n]);
            }
        }
        __syncthreads();
    }

    const float scale = 0.011048543456039806f;  // 1/sqrt(32*256)
#pragma unroll
    for (int m = 0; m < 4; m++) {
#pragma unroll
        for (int r = 0; r < 4; r++) {
            int q = q0 + m * 16 + lg * 4 + r;
            float* dst = Sc + ((size_t)bh * 256 + q) * 256 + ks0 + n0;
#pragma unroll
            for (int n = 0; n < 2; n++)
                dst[n * 16 + lr] = acc[m][n][r] * scale;
        }
    }
}

// ---------------------------------------------------------------------------
// Kernel 2b: row softmax (f32 in, bf16 probs out).  grid 2048, block 256.
// One wave per row of 256; 4 elements per lane.
// ---------------------------------------------------------------------------
__global__ __launch_bounds__(256) void k_softmax(
    const float* __restrict__ Sc, unsigned short* __restrict__ Pb)
{
    const int tid = threadIdx.x;
    const int wv = tid >> 6, ln = tid & 63;
    const int row = blockIdx.x * 4 + wv;

    f32x4 v = *(const f32x4*)(Sc + (size_t)row * 256 + ln * 4);
    float m = fmaxf(fmaxf(v.x, v.y), fmaxf(v.z, v.w));
#pragma unroll
    for (int off = 32; off; off >>= 1) m = fmaxf(m, __shfl_xor(m, off));
    float e0 = __expf(v.x - m), e1 = __expf(v.y - m);
    float e2 = __expf(v.z - m), e3 = __expf(v.w - m);
    float sum = e0 + e1 + e2 + e3;
#pragma unroll
    for (int off = 32; off; off >>= 1) sum += __shfl_xor(sum, off);
    float inv = 1.f / sum;
    s16x4 p = {(short)f2bf(e0 * inv), (short)f2bf(e1 * inv),
               (short)f2bf(e2 * inv), (short)f2bf(e3 * inv)};
    *(s16x4*)(Pb + (size_t)row * 256 + ln * 4) = p;
}

// ---------------------------------------------------------------------------
// Kernel 2c: SA = P V.  grid (128, 32), block 256.
// blockIdx.x = qt*32 + ft; per block [64 q x 256 f] for d=ft, K=256 (ks).
// Wave: [64 m x 64 n]; m-frags 4, n-frags 4.
// ---------------------------------------------------------------------------
__global__ __launch_bounds__(256, 2) void k_av(
    const unsigned short* __restrict__ Pb, const unsigned short* __restrict__ Vb,
    unsigned short* __restrict__ SAb)
{
    const int bh = blockIdx.y;
    const int qt = blockIdx.x >> 5;
    const int ft = blockIdx.x & 31;    // == d
    const int q0 = qt * 64;
    const int b = bh >> 3, h = bh & 7;
    const int tid = threadIdx.x;
    const int wv = tid >> 6, ln = tid & 63;
    const int lg = ln >> 4, lr = ln & 15;
    const int n0 = wv * 64;

    __shared__ __align__(16) unsigned short Pl[64][264];   // P tile, whole K=256
    __shared__ __align__(16) unsigned short Vl[32][264];   // V chunk [32 ks][256 p]

    {   // stage P whole: 64x256, 64 el/thread
        int r = tid >> 2, c0 = (tid & 3) * 64;
        const unsigned short* src = Pb + (size_t)(bh * 256 + q0 + r) * 256 + c0;
#pragma unroll
        for (int i = 0; i < 8; i++)
            *(s16x8*)&Pl[r][c0 + i * 8] = *(const s16x8*)(src + i * 8);
    }

    f32x4 acc[4][4];
    const f32x4 z4 = {0.f, 0.f, 0.f, 0.f};
#pragma unroll
    for (int m = 0; m < 4; m++)
#pragma unroll
        for (int n = 0; n < 4; n++) acc[m][n] = z4;

    for (int k0 = 0; k0 < 256; k0 += 32) {
        {   // stage V chunk 32x256
            int r = tid >> 3, c0 = (tid & 7) * 32;
            const unsigned short* src =
                Vb + ((size_t)(bh * 256 + k0 + r)) * 8192 + (size_t)ft * 256 + c0;
#pragma unroll
            for (int i = 0; i < 4; i++)
                *(s16x8*)&Vl[r][c0 + i * 8] = *(const s16x8*)(src + i * 8);
        }
        __syncthreads();

        s16x8 af[4];
#pragma unroll
        for (int m = 0; m < 4; m++)
            af[m] = *(const s16x8*)&Pl[m * 16 + lr][k0 + lg * 8];
#pragma unroll
        for (int n = 0; n < 4; n++) {
            s16x8 bf;
            int col = n0 + n * 16 + lr;
#pragma unroll
            for (int j = 0; j < 8; j++) bf[j] = (short)Vl[lg * 8 + j][col];
            bf16x8 bv = asbf(bf);
#pragma unroll
            for (int m = 0; m < 4; m++)
                acc[m][n] = MFMA16(asbf(af[m]), bv, acc[m][n]);
        }
        __syncthreads();
    }

    // store SA in [bs][c][p] layout, c = h*32 + d
#pragma unroll
    for (int m = 0; m < 4; m++) {
#pragma unroll
        for (int r = 0; r < 4; r++) {
            int sq = q0 + m * 16 + lg * 4 + r;
            unsigned short* dst =
                SAb + ((size_t)((b * 256 + sq) * 256 + h * 32 + ft)) * 256 + n0;
#pragma unroll
            for (int n = 0; n < 4; n++)
                dst[n * 16 + lr] = f2bf(acc[m][n][r]);
        }
    }
}

// ---------------------------------------------------------------------------
// Kernel 3: out = W_out SA + b.  grid (2, 1024), block 256.
// Same structure as k_qkv; B already bf16; fp32 coalesced stores.
// ---------------------------------------------------------------------------
__global__ __launch_bounds__(256, 2) void k_out(
    const unsigned short* __restrict__ SAb, const float* __restrict__ W,
    const float* __restrict__ bias, float* __restrict__ out)
{
    const int bs = blockIdx.y;
    const int mt = blockIdx.x;
    const int tid = threadIdx.x;
    const int wv = tid >> 6, ln = tid & 63;
    const int lg = ln >> 4, lr = ln & 15;
    const int n0 = wv * 64;

    __shared__ __align__(16) unsigned short Al[128][72];
    __shared__ __align__(16) unsigned short Bl[32][264];

    f32x4 acc[8][4];
    const f32x4 z4 = {0.f, 0.f, 0.f, 0.f};
#pragma unroll
    for (int m = 0; m < 8; m++)
#pragma unroll
        for (int n = 0; n < 4; n++) acc[m][n] = z4;

    const float* Wt = W + (size_t)mt * 128 * 256;
    const unsigned short* Bsrc = SAb + (size_t)bs * 65536;

    for (int k0 = 0; k0 < 256; k0 += 32) {
        {   // stage A (W_out rows, fp32 -> bf16)
            int r = tid >> 1, c0 = (tid & 1) * 16;
            const float* src = Wt + (size_t)r * 256 + k0 + c0;
#pragma unroll
            for (int i = 0; i < 4; i++) {
                f32x4 v = *(const f32x4*)(src + i * 4);
                s16x4 h = {(short)f2bf(v.x), (short)f2bf(v.y), (short)f2bf(v.z), (short)f2bf(v.w)};
                *(s16x4*)&Al[r][c0 + i * 4] = h;
            }
        }
        {   // stage B (SA chunk, bf16 copy): 32x256
            int r = tid >> 3, c0 = (tid & 7) * 32;
            const unsigned short* src = Bsrc + (size_t)(k0 + r) * 256 + c0;
#pragma unroll
            for (int i = 0; i < 4; i++)
                *(s16x8*)&Bl[r][c0 + i * 8] = *(const s16x8*)(src + i * 8);
        }
        __syncthreads();

        s16x8 af[8];
#pragma unroll
        for (int m = 0; m < 8; m++)
            af[m] = *(const s16x8*)&Al[m * 16 + lr][lg * 8];
#pragma unroll
        for (int n = 0; n < 4; n++) {
            s16x8 bf;
            int col = n0 + n * 16 + lr;
#pragma unroll
            for (int j = 0; j < 8; j++) bf[j] = (short)Bl[lg * 8 + j][col];
            bf16x8 bv = asbf(bf);
#pragma unroll
            for (int m = 0; m < 8; m++)
                acc[m][n] = MFMA16(asbf(af[m]), bv, acc[m][n]);
        }
        __syncthreads();
    }

#pragma unroll
    for (int m = 0; m < 8; m++) {
#pragma unroll
        for (int r = 0; r < 4; r++) {
            int o = mt * 128 + m * 16 + lg * 4 + r;
            float bo = bias[o];
            float* dst = out + ((size_t)bs * 256 + o) * 256 + n0;
#pragma unroll
            for (int n = 0; n < 4; n++)
                dst[n * 16 + lr] = acc[m][n][r] + bo;
        }
    }
}

// ---------------------------------------------------------------------------
extern "C" void kernel_launch(void* const* d_in, const int* in_sizes, int n_in,
                              void* d_out, int out_size, void* d_ws, size_t ws_size,
                              hipStream_t stream)
{
    const float* seq  = (const float*)d_in[0];
    const float* Wqkv = (const float*)d_in[1];
    const float* Wout = (const float*)d_in[2];
    const float* bout = (const float*)d_in[3];

    // Q,K live in d_out (exactly 2 x 128 MiB bf16); overwritten by k_out at the end.
    unsigned short* Qb = (unsigned short*)d_out;
    unsigned short* Kb = Qb + 67108864;

    // d_ws: V (128 MiB) | SA (128 MiB) | scores (8 MiB f32) | P (4 MiB bf16)
    unsigned short* Vb  = (unsigned short*)d_ws;
    unsigned short* SAb = Vb + 67108864;
    float*          Sc  = (float*)(SAb + 67108864);
    unsigned short* Pb  = (unsigned short*)(Sc + 2097152);

    float* out = (float*)d_out;

    k_qkv<<<dim3(6, 1024), dim3(256), 0, stream>>>(seq, Wqkv, Qb, Kb, Vb);
    k_scores<<<dim3(8, 32), dim3(256), 0, stream>>>(Qb, Kb, Sc);
    k_softmax<<<dim3(2048), dim3(256), 0, stream>>>(Sc, Pb);
    k_av<<<dim3(128, 32), dim3(256), 0, stream>>>(Pb, Vb, SAb);
    k_out<<<dim3(2, 1024), dim3(256), 0, stream>>>(SAb, Wout, bout, out);
}

// Round 3
// 604.788 us; speedup vs baseline: 1.2326x; 1.2326x over previous
//
#include <hip/hip_runtime.h>
#include <stdint.h>

// FuncSelfAttention: b=4, s=256, E=256, H=8, d=32, p=16x16=256
// All GEMMs bf16 MFMA 16x16x32, fp32 accumulate. No tr-read, no subtiled LDS:
// every fragment is read as [row][k] from XOR-swizzled linear LDS (verified
// pattern); NN-GEMMs transpose their B operand during staging (scalar column
// loads + vector ds_write_b64 into the same swizzled layout).
//
// Tiles: BM=256, BN=128, BK=64, 4 waves of 128x64 (k_scores: BM=128, 64x64).
//
// Memory (round-1-proven envelope):
//   d_out: Qb 128 MiB | Kb 128 MiB (dead before k_out writes the 64 MiB output)
//   d_ws : Vb 128 | SAb 128 (Sp f32 16 MiB overlaid, dead before k_av) |
//          Pb 4 | Wbf 0.5   => peak 260.5 MiB

#define DI __device__ __forceinline__

typedef __attribute__((ext_vector_type(4))) float  f32x4;
typedef __attribute__((ext_vector_type(8))) short  s16x8;
typedef __attribute__((ext_vector_type(4))) short  s16x4;
typedef __attribute__((ext_vector_type(8))) __bf16 bf16x8;

DI unsigned short f2bf(float f) {
    unsigned int u = __builtin_bit_cast(unsigned int, f);
    u = (u + 0x7fffu + ((u >> 16) & 1u)) >> 16;
    return (unsigned short)u;
}
DI bf16x8 asbf(s16x8 v) { return __builtin_bit_cast(bf16x8, v); }
#define MFMA16(a, b, c) __builtin_amdgcn_mfma_f32_16x16x32_bf16((a), (b), (c), 0, 0, 0)

// ---- stage A [256 rows][64 k] bf16, one row per thread, chunk-XOR swizzle ---
DI void stage_a256(unsigned short* __restrict__ T,
                   const unsigned short* __restrict__ src, int stride, int tid) {
    const unsigned short* s = src + (size_t)tid * stride;
    int r7 = tid & 7;
#pragma unroll
    for (int ch = 0; ch < 8; ch++) {
        s16x8 v = *(const s16x8*)(s + ch * 8);
        *(s16x8*)&T[tid * 64 + ((ch ^ r7) << 3)] = v;
    }
}

// ---- stage [128 rows][64 k] bf16, two threads per row (k_scores) ------------
DI void stage_l128(unsigned short* __restrict__ T,
                   const unsigned short* __restrict__ src, int stride, int tid) {
    int row = tid >> 1, c4 = (tid & 1) * 4, r7 = row & 7;
    const unsigned short* s = src + (size_t)row * stride;
#pragma unroll
    for (int i = 0; i < 4; i++) {
        s16x8 v = *(const s16x8*)(s + (c4 + i) * 8);
        *(s16x8*)&T[row * 64 + (((c4 + i) ^ r7) << 3)] = v;
    }
}

// ---- stage TRANSPOSED: src [64 k][stride] bf16 -> BT[128 p][64 k] swizzled --
// thread handles column p = tid&127; c-quads (tid>>7) + 2i.
DI void stage_tr16(unsigned short* __restrict__ BT,
                   const unsigned short* __restrict__ src, int stride, int tid) {
    int p = tid & 127, cqh = tid >> 7, p7 = p & 7;
#pragma unroll
    for (int i = 0; i < 8; i++) {
        int cq = cqh + 2 * i;
        int cb = cq * 4;
        unsigned short e0 = src[(size_t)(cb + 0) * stride + p];
        unsigned short e1 = src[(size_t)(cb + 1) * stride + p];
        unsigned short e2 = src[(size_t)(cb + 2) * stride + p];
        unsigned short e3 = src[(size_t)(cb + 3) * stride + p];
        s16x4 v = {(short)e0, (short)e1, (short)e2, (short)e3};
        *(s16x4*)&BT[p * 64 + (((cq >> 1) ^ p7) << 3) + (cq & 1) * 4] = v;
    }
}

// ---- same but f32 source with bf16 convert ----------------------------------
DI void stage_tr32(unsigned short* __restrict__ BT,
                   const float* __restrict__ src, int stride, int tid) {
    int p = tid & 127, cqh = tid >> 7, p7 = p & 7;
#pragma unroll
    for (int i = 0; i < 8; i++) {
        int cq = cqh + 2 * i;
        int cb = cq * 4;
        float e0 = src[(size_t)(cb + 0) * stride + p];
        float e1 = src[(size_t)(cb + 1) * stride + p];
        float e2 = src[(size_t)(cb + 2) * stride + p];
        float e3 = src[(size_t)(cb + 3) * stride + p];
        s16x4 v = {(short)f2bf(e0), (short)f2bf(e1), (short)f2bf(e2), (short)f2bf(e3)};
        *(s16x4*)&BT[p * 64 + (((cq >> 1) ^ p7) << 3) + (cq & 1) * 4] = v;
    }
}

// ---- MFMA phase, wave tile 128x64 (mf=8, nf=4), BK=64 -----------------------
DI void mfma_84(const unsigned short* __restrict__ Al,
                const unsigned short* __restrict__ Bl,
                f32x4 acc[8][4], int wm, int wn, int lg, int lr) {
#pragma unroll
    for (int kk = 0; kk < 2; kk++) {
        int off = (((kk * 4 + lg) ^ (lr & 7)) << 3);
        s16x8 af[8];
#pragma unroll
        for (int m = 0; m < 8; m++)
            af[m] = *(const s16x8*)&Al[(wm + m * 16 + lr) * 64 + off];
        s16x8 bf[4];
#pragma unroll
        for (int n = 0; n < 4; n++)
            bf[n] = *(const s16x8*)&Bl[(wn + n * 16 + lr) * 64 + off];
#pragma unroll
        for (int n = 0; n < 4; n++) {
            bf16x8 bv = asbf(bf[n]);
#pragma unroll
            for (int m = 0; m < 8; m++)
                acc[m][n] = MFMA16(asbf(af[m]), bv, acc[m][n]);
        }
    }
}

// ---- MFMA phase, wave tile 64x64 (mf=4, nf=4) (k_scores) --------------------
DI void mfma_44(const unsigned short* __restrict__ Al,
                const unsigned short* __restrict__ Bl,
                f32x4 acc[4][4], int wm, int wn, int lg, int lr) {
#pragma unroll
    for (int kk = 0; kk < 2; kk++) {
        int off = (((kk * 4 + lg) ^ (lr & 7)) << 3);
        s16x8 af[4];
#pragma unroll
        for (int m = 0; m < 4; m++)
            af[m] = *(const s16x8*)&Al[(wm + m * 16 + lr) * 64 + off];
        s16x8 bf[4];
#pragma unroll
        for (int n = 0; n < 4; n++)
            bf[n] = *(const s16x8*)&Bl[(wn + n * 16 + lr) * 64 + off];
#pragma unroll
        for (int n = 0; n < 4; n++) {
            bf16x8 bv = asbf(bf[n]);
#pragma unroll
            for (int m = 0; m < 4; m++)
                acc[m][n] = MFMA16(asbf(af[m]), bv, acc[m][n]);
        }
    }
}

// ===========================================================================
// k_prep: Wbf[1024][256] bf16: rows 0..767 = W_qkv permuted split-major
// (r = split*256 + h*32 + dd  <-  source row h*96 + split*32 + dd),
// rows 768..1023 = W_out.
// ===========================================================================
__global__ __launch_bounds__(64) void k_prep(
    const float* __restrict__ Wqkv, const float* __restrict__ Wout,
    unsigned short* __restrict__ Wbf)
{
    int r = blockIdx.x, ln = threadIdx.x;
    const float* src;
    if (r < 768) {
        int split = r >> 8, hd = r & 255;
        src = Wqkv + (size_t)(((hd >> 5) * 96) + split * 32 + (hd & 31)) * 256;
    } else {
        src = Wout + (size_t)(r - 768) * 256;
    }
    f32x4 v = *(const f32x4*)(src + ln * 4);
    s16x4 h = {(short)f2bf(v.x), (short)f2bf(v.y), (short)f2bf(v.z), (short)f2bf(v.w)};
    *(s16x4*)&Wbf[(size_t)r * 256 + ln * 4] = h;
}

// ===========================================================================
// k_qkv: per bs: [768 o x 256 c] x [256 c x 256 p].  grid 6144.
// XCD-chunked swizzle so the 6 blocks of one bs share an XCD/L2.
// mt (0..2) == split (Q/K/V). BN=128 via nt.
// ===========================================================================
__global__ __launch_bounds__(256, 2) void k_qkv(
    const float* __restrict__ seq, const unsigned short* __restrict__ Wbf,
    unsigned short* __restrict__ Qb, unsigned short* __restrict__ Kb,
    unsigned short* __restrict__ Vb)
{
    const int bid = blockIdx.x;
    const int wk = (bid & 7) * 768 + (bid >> 3);
    const int bs = wk / 6, r6 = wk - bs * 6;
    const int mt = r6 >> 1, nt = r6 & 1;
    const int b = bs >> 8, s = bs & 255;
    const int tid = threadIdx.x, ln = tid & 63, wv = tid >> 6;
    const int wm = (wv >> 1) * 128, wn = (wv & 1) * 64;
    const int lg = ln >> 4, lr = ln & 15;

    __shared__ __align__(16) unsigned short Al[256 * 64];
    __shared__ __align__(16) unsigned short Bt[128 * 64];

    f32x4 acc[8][4];
    const f32x4 z4 = {0.f, 0.f, 0.f, 0.f};
#pragma unroll
    for (int m = 0; m < 8; m++)
#pragma unroll
        for (int n = 0; n < 4; n++) acc[m][n] = z4;

    const unsigned short* Asrc = Wbf + (size_t)mt * 256 * 256;
    const float* Bsrc = seq + (size_t)bs * 65536 + nt * 128;

    for (int k0 = 0; k0 < 256; k0 += 64) {
        stage_a256(Al, Asrc + k0, 256, tid);
        stage_tr32(Bt, Bsrc + (size_t)k0 * 256, 256, tid);
        __syncthreads();
        mfma_84(Al, Bt, acc, wm, wn, lg, lr);
        __syncthreads();
    }

    unsigned short* dst = (mt == 0) ? Qb : (mt == 1) ? Kb : Vb;
#pragma unroll
    for (int m = 0; m < 8; m++) {
#pragma unroll
        for (int rr = 0; rr < 4; rr++) {
            int o = wm + m * 16 + lg * 4 + rr;      // 0..255 within split
            size_t base = ((size_t)((b * 8 + (o >> 5)) * 256 + s)) * 8192
                        + (size_t)(o & 31) * 256 + nt * 128 + wn + lr;
#pragma unroll
            for (int n = 0; n < 4; n++)
                dst[base + n * 16] = f2bf(acc[m][n][rr]);
        }
    }
}

// ===========================================================================
// k_scores: partial Q K^T (NT).  grid (8, 32): x = qt*4 + kc*2 + st, y = bh.
// K-range 4096 per kc; Sp[kc][bh][q][ks] f32 unscaled.
// ===========================================================================
__global__ __launch_bounds__(256, 3) void k_scores(
    const unsigned short* __restrict__ Qb, const unsigned short* __restrict__ Kb,
    float* __restrict__ Sp)
{
    const int bh = blockIdx.y;
    const int qt = blockIdx.x >> 2, kc = (blockIdx.x >> 1) & 1, st = blockIdx.x & 1;
    const int tid = threadIdx.x, ln = tid & 63, wv = tid >> 6;
    const int wm = (wv >> 1) * 64, wn = (wv & 1) * 64;
    const int lg = ln >> 4, lr = ln & 15;

    __shared__ __align__(16) unsigned short Al[128 * 64];
    __shared__ __align__(16) unsigned short Bl[128 * 64];

    f32x4 acc[4][4];
    const f32x4 z4 = {0.f, 0.f, 0.f, 0.f};
#pragma unroll
    for (int m = 0; m < 4; m++)
#pragma unroll
        for (int n = 0; n < 4; n++) acc[m][n] = z4;

    const unsigned short* Asrc = Qb + (size_t)(bh * 256 + qt * 128) * 8192 + kc * 4096;
    const unsigned short* Bsrc = Kb + (size_t)(bh * 256 + st * 128) * 8192 + kc * 4096;

    for (int t = 0; t < 64; t++) {
        stage_l128(Al, Asrc + t * 64, 8192, tid);
        stage_l128(Bl, Bsrc + t * 64, 8192, tid);
        __syncthreads();
        mfma_44(Al, Bl, acc, wm, wn, lg, lr);
        __syncthreads();
    }

    float* dst = Sp + (size_t)kc * 2097152
               + ((size_t)(bh * 256) + qt * 128 + wm) * 256 + st * 128 + wn;
#pragma unroll
    for (int m = 0; m < 4; m++) {
#pragma unroll
        for (int rr = 0; rr < 4; rr++) {
            float* d = dst + (size_t)(m * 16 + lg * 4 + rr) * 256 + lr;
#pragma unroll
            for (int n = 0; n < 4; n++)
                d[n * 16] = acc[m][n][rr];
        }
    }
}

// ===========================================================================
// k_softmax: sum kc=2 partials, scale, softmax, P bf16.  grid 2048 x 256.
// ===========================================================================
__global__ __launch_bounds__(256) void k_softmax(
    const float* __restrict__ Sp, unsigned short* __restrict__ Pb)
{
    const int tid = threadIdx.x, ln = tid & 63;
    const int row = blockIdx.x * 4 + (tid >> 6);
    const float scale = 0.011048543456039806f;  // 1/sqrt(32*256)

    const float* p0 = Sp + (size_t)row * 256 + ln * 4;
    f32x4 a = *(const f32x4*)p0;
    f32x4 c = *(const f32x4*)(p0 + 2097152);
    f32x4 v = (a + c) * scale;

    float m = fmaxf(fmaxf(v.x, v.y), fmaxf(v.z, v.w));
#pragma unroll
    for (int off = 32; off; off >>= 1) m = fmaxf(m, __shfl_xor(m, off));
    float e0 = __expf(v.x - m), e1 = __expf(v.y - m);
    float e2 = __expf(v.z - m), e3 = __expf(v.w - m);
    float sum = e0 + e1 + e2 + e3;
#pragma unroll
    for (int off = 32; off; off >>= 1) sum += __shfl_xor(sum, off);
    float inv = 1.f / sum;
    s16x4 p = {(short)f2bf(e0 * inv), (short)f2bf(e1 * inv),
               (short)f2bf(e2 * inv), (short)f2bf(e3 * inv)};
    *(s16x4*)(Pb + (size_t)row * 256 + ln * 4) = p;
}

// ===========================================================================
// k_av: SA = P V (NN, B transposed in staging).  grid (64, 32): x = ft, y = bh.
// BM=256 (all q), BN=128 (f-slice); f = ft*128 + n-col.
// ===========================================================================
__global__ __launch_bounds__(256, 2) void k_av(
    const unsigned short* __restrict__ Pb, const unsigned short* __restrict__ Vb,
    unsigned short* __restrict__ SAb)
{
    const int ft = blockIdx.x, bh = blockIdx.y;
    const int b = bh >> 3, h = bh & 7;
    const int tid = threadIdx.x, ln = tid & 63, wv = tid >> 6;
    const int wm = (wv >> 1) * 128, wn = (wv & 1) * 64;
    const int lg = ln >> 4, lr = ln & 15;

    __shared__ __align__(16) unsigned short Al[256 * 64];
    __shared__ __align__(16) unsigned short Bt[128 * 64];

    f32x4 acc[8][4];
    const f32x4 z4 = {0.f, 0.f, 0.f, 0.f};
#pragma unroll
    for (int m = 0; m < 8; m++)
#pragma unroll
        for (int n = 0; n < 4; n++) acc[m][n] = z4;

    const unsigned short* Asrc = Pb + (size_t)(bh * 256) * 256;
    const unsigned short* Bsrc = Vb + (size_t)(bh * 256) * 8192 + ft * 128;

    for (int k0 = 0; k0 < 256; k0 += 64) {
        stage_a256(Al, Asrc + k0, 256, tid);
        stage_tr16(Bt, Bsrc + (size_t)k0 * 8192, 8192, tid);
        __syncthreads();
        mfma_84(Al, Bt, acc, wm, wn, lg, lr);
        __syncthreads();
    }

    const int cc = h * 32 + (ft >> 1);
    const int pb = (ft & 1) * 128;
#pragma unroll
    for (int m = 0; m < 8; m++) {
#pragma unroll
        for (int rr = 0; rr < 4; rr++) {
            int q = wm + m * 16 + lg * 4 + rr;
            size_t base = ((size_t)(b * 256 + q) * 256 + cc) * 256 + pb + wn + lr;
#pragma unroll
            for (int n = 0; n < 4; n++)
                SAb[base + n * 16] = f2bf(acc[m][n][rr]);
        }
    }
}

// ===========================================================================
// k_out: out = W_out SA + b (NN, B transposed in staging).
// grid (2, 1024): x = nt, y = bs.  BM=256 (all o), BN=128.
// ===========================================================================
__global__ __launch_bounds__(256, 2) void k_out(
    const unsigned short* __restrict__ SAb, const unsigned short* __restrict__ Wbf,
    const float* __restrict__ bias, float* __restrict__ out)
{
    const int nt = blockIdx.x, bs = blockIdx.y;
    const int tid = threadIdx.x, ln = tid & 63, wv = tid >> 6;
    const int wm = (wv >> 1) * 128, wn = (wv & 1) * 64;
    const int lg = ln >> 4, lr = ln & 15;

    __shared__ __align__(16) unsigned short Al[256 * 64];
    __shared__ __align__(16) unsigned short Bt[128 * 64];

    f32x4 acc[8][4];
    const f32x4 z4 = {0.f, 0.f, 0.f, 0.f};
#pragma unroll
    for (int m = 0; m < 8; m++)
#pragma unroll
        for (int n = 0; n < 4; n++) acc[m][n] = z4;

    const unsigned short* Asrc = Wbf + (size_t)768 * 256;
    const unsigned short* Bsrc = SAb + (size_t)bs * 65536 + nt * 128;

    for (int k0 = 0; k0 < 256; k0 += 64) {
        stage_a256(Al, Asrc + k0, 256, tid);
        stage_tr16(Bt, Bsrc + (size_t)k0 * 256, 256, tid);
        __syncthreads();
        mfma_84(Al, Bt, acc, wm, wn, lg, lr);
        __syncthreads();
    }

#pragma unroll
    for (int m = 0; m < 8; m++) {
#pragma unroll
        for (int rr = 0; rr < 4; rr++) {
            int o = wm + m * 16 + lg * 4 + rr;
            float bo = bias[o];
            float* d = out + ((size_t)bs * 256 + o) * 256 + nt * 128 + wn + lr;
#pragma unroll
            for (int n = 0; n < 4; n++)
                d[n * 16] = acc[m][n][rr] + bo;
        }
    }
}

// ---------------------------------------------------------------------------
extern "C" void kernel_launch(void* const* d_in, const int* in_sizes, int n_in,
                              void* d_out, int out_size, void* d_ws, size_t ws_size,
                              hipStream_t stream)
{
    const float* seq  = (const float*)d_in[0];
    const float* Wqkv = (const float*)d_in[1];
    const float* Wout = (const float*)d_in[2];
    const float* bout = (const float*)d_in[3];

    // d_out: Q | K (dead before k_out writes the final 64 MiB at the base)
    unsigned short* Qb = (unsigned short*)d_out;
    unsigned short* Kb = Qb + 67108864;

    // d_ws: V | SA (Sp overlaid) | P | Wbf   (peak 260.5 MiB)
    unsigned short* Vb  = (unsigned short*)d_ws;
    unsigned short* SAb = Vb + 67108864;
    float*          Sp  = (float*)SAb;
    unsigned short* Pb  = (unsigned short*)d_ws + 134217728;
    unsigned short* Wbf = Pb + 2097152;

    float* out = (float*)d_out;

    k_prep<<<dim3(1024), dim3(64), 0, stream>>>(Wqkv, Wout, Wbf);
    k_qkv<<<dim3(6144), dim3(256), 0, stream>>>(seq, Wbf, Qb, Kb, Vb);
    k_scores<<<dim3(8, 32), dim3(256), 0, stream>>>(Qb, Kb, Sp);
    k_softmax<<<dim3(2048), dim3(256), 0, stream>>>(Sp, Pb);
    k_av<<<dim3(64, 32), dim3(256), 0, stream>>>(Pb, Vb, SAb);
    k_out<<<dim3(2, 1024), dim3(256), 0, stream>>>(SAb, Wbf, bout, out);
}